// Round 11
// baseline (373.376 us; speedup 1.0000x reference)
//
#include <hip/hip_runtime.h>
#include <hip/hip_bf16.h>
#include <stdint.h>

// MoveCenterPts: out = where(MOD & (feat != 0), clip(feat + deltas@COEF.T, 0, LIM), feat)
// Static layout over d in [0,2217): head segments (meta-table) for d<457,
// pure 2-phase (OX+JX)/(OY+JY) pattern for d in [457,2217).
//
// Round-9 structure: BLOCK-PER-FRAME ablation/optimization.
//   t = blockIdx.x  -> deltas are block-uniform (scalar loads), NO per-group div.
//   Row r starts at element r*2217 (odd stride): <=3 scalar head elems to reach
//   16B alignment, <=3 scalar tail elems; aligned middle processed as f32x4.
//   Fast groups (d0>=457): parity of element j is (align_off+j)&1 — BLOCK-UNIFORM,
//   so off/lim selection hoists out of the loop. Generic groups (d0<457, ~20%)
//   use the packed meta table (d_ws, rebuilt each call: ws is re-poisoned).
//   meta bits: 0 mod | 1 hasB | 2 lim720 | 3-5 idxA | 6-8 idxB

#define D_FEAT 2217u
typedef float f32x4 __attribute__((ext_vector_type(4)));

__global__ void build_meta_kernel(uint32_t* __restrict__ meta) {
    int d = blockIdx.x * blockDim.x + threadIdx.x;
    if (d >= (int)D_FEAT) return;

    int a = 0, b = 0;
    bool mod = true, hasB = false;

    if (d == 0 || d == 83 || d == 168) {
        mod = false;
    } else if (d <= 80) {
        int o = d - 1;
        if ((o & 1) == 0) { a = 0; b = 4; } else { a = 1; b = 5; }
        hasB = true;
    } else if (d == 81) { a = 0;
    } else if (d == 82) { a = 1;
    } else if (d <= 163) {
        int o = d - 84;
        if ((o & 1) == 0) { a = 2; b = 4; } else { a = 3; b = 5; }
        hasB = true;
    } else if (d == 164) { a = 2;
    } else if (d == 165) { a = 3;
    } else if (d == 166) { a = 0; b = 2; hasB = true;
    } else if (d == 167) { a = 1; b = 3; hasB = true;
    } else if (d <= 368) {
        int o = (d - 169) % 5;
        if (o < 3) { mod = false; }
        else if (o == 3) { a = 4; }
        else { a = 5; }
    } else if (d <= 412) {
        int o = d - 369;
        if ((o & 1) == 0) { a = 2; b = 6; } else { a = 3; b = 7; }
        hasB = true;
    } else if (d <= 456) {
        int o = d - 413;
        if ((o & 1) == 0) { a = 0; b = 6; } else { a = 1; b = 7; }
        hasB = true;
    } else {
        int o = d - 457;
        if ((o & 1) == 0) { a = 4; b = 6; } else { a = 5; b = 7; }
        hasB = true;
    }

    uint32_t limH = (uint32_t)(a & 1);  // odd delta index => y => lim 720
    uint32_t pack = (mod ? 1u : 0u) | (hasB ? 2u : 0u) | (limH << 2)
                  | ((uint32_t)a << 3) | ((uint32_t)b << 6);
    meta[d] = pack;
}

// generic meta-driven transform for one element (any d)
__device__ __forceinline__ float xform_meta(float f, uint32_t p,
                                            const float* __restrict__ dl) {
    float dA = dl[(p >> 3) & 7u];
    float dB = dl[(p >> 6) & 7u];
    float off = dA + ((p & 2u) ? dB : 0.0f);
    float lim = (p & 4u) ? 720.0f : 1280.0f;
    float s = fminf(fmaxf(f + off, 0.0f), lim);
    return ((p & 1u) && (f != 0.0f)) ? s : f;
}

__global__ __launch_bounds__(192) void move_center_pts_kernel(
    const float* __restrict__ feat,
    const float* __restrict__ deltas,
    const uint32_t* __restrict__ meta,
    float* __restrict__ out) {
    unsigned r = blockIdx.x;                 // frame index, grid.x == T
    size_t base = (size_t)r * D_FEAT;
    const float* dl = deltas + (size_t)r * 8u;   // block-uniform -> scalar loads

    float offx = dl[4] + dl[6];              // OX + JX
    float offy = dl[5] + dl[7];              // OY + JY

    unsigned align_off = (unsigned)((4u - ((unsigned)base & 3u)) & 3u);
    size_t a0 = base + align_off;            // first 16B-aligned element
    unsigned L = D_FEAT - align_off;
    unsigned ngroups = L >> 2;               // aligned f32x4 groups
    unsigned tail_rem = L & 3u;              // trailing scalars
    unsigned tid = threadIdx.x;

    // scalar head (d = 0..align_off-1) and tail (d >= 2214-ish), via meta path
    if (tid < align_off) {
        float f = feat[base + tid];
        out[base + tid] = xform_meta(f, meta[tid], dl);
    }
    if (tid < tail_rem) {
        unsigned d = align_off + (ngroups << 2) + tid;
        float f = feat[base + d];
        out[base + d] = xform_meta(f, meta[d], dl);
    }

    // block-uniform parity: element j of any group has d parity (align_off+j)&1
    bool odd0 = (align_off & 1u) != 0u;      // parity of j=0 element
    // d odd => x slot (lim 1280), d even => y slot (lim 720)
    float offA = odd0 ? offx : offy, limA = odd0 ? 1280.0f : 720.0f;
    float offB = odd0 ? offy : offx, limB = odd0 ? 720.0f : 1280.0f;

    const f32x4* f4p = reinterpret_cast<const f32x4*>(feat + a0);
    f32x4* o4p = reinterpret_cast<f32x4*>(out + a0);

    for (unsigned g = tid; g < ngroups; g += 192u) {
        unsigned d0 = align_off + (g << 2);
        f32x4 f4 = f4p[g];
        f32x4 o4;
        if (d0 >= 457u) {
            // fast 2-phase region; selection block-uniform, hoisted above
            float f, s;
            f = f4.x; s = fminf(fmaxf(f + offA, 0.0f), limA); o4.x = (f != 0.0f) ? s : f;
            f = f4.y; s = fminf(fmaxf(f + offB, 0.0f), limB); o4.y = (f != 0.0f) ? s : f;
            f = f4.z; s = fminf(fmaxf(f + offA, 0.0f), limA); o4.z = (f != 0.0f) ? s : f;
            f = f4.w; s = fminf(fmaxf(f + offB, 0.0f), limB); o4.w = (f != 0.0f) ? s : f;
        } else {
            // head region: meta-driven (handles skip slots, paired deltas, mixed lims)
            o4.x = xform_meta(f4.x, meta[d0 + 0u], dl);
            o4.y = xform_meta(f4.y, meta[d0 + 1u], dl);
            o4.z = xform_meta(f4.z, meta[d0 + 2u], dl);
            o4.w = xform_meta(f4.w, meta[d0 + 3u], dl);
        }
        o4p[g] = o4;
    }
}

extern "C" void kernel_launch(void* const* d_in, const int* in_sizes, int n_in,
                              void* d_out, int out_size, void* d_ws, size_t ws_size,
                              hipStream_t stream) {
    const float* feat   = (const float*)d_in[0];   // [T, 2217] f32
    const float* deltas = (const float*)d_in[1];   // [T, 8] f32
    float* out = (float*)d_out;
    uint32_t* meta = (uint32_t*)d_ws;              // 2217 * 4 B scratch

    // rebuild metadata every call (d_ws is re-poisoned before each timed launch)
    build_meta_kernel<<<(D_FEAT + 255) / 256, 256, 0, stream>>>(meta);

    unsigned T = (unsigned)(in_sizes[0] / (int)D_FEAT);   // 25000
    // block-per-frame: 192 threads (3 waves) x ceil(555/192)=3 iters, 96% util
    move_center_pts_kernel<<<T, 192, 0, stream>>>(feat, deltas, meta, out);
}